// Round 1
// baseline (454.495 us; speedup 1.0000x reference)
//
#include <hip/hip_runtime.h>

// ---------------------------------------------------------------------------
// Attention: y = softmax( (xWq^T)(xWk^T)^T / sqrt(128) ) (xWv^T)
// B=4, N=4096, H=OUT=128. fp32 I/O, bf16 MFMA compute.
//
// Pipeline:
//   proj_qk : q'' = (x Wq^T) * (1/sqrt(128) * log2(e))  -> bf16 [B*N][128]
//             k   = (x Wk^T)                             -> bf16 [B*N][128]
//   proj_vt : v^T = (x Wv^T)^T                           -> bf16 [B][128][4096]
//   flash   : per 64-q-row block, stream K in 64-key tiles:
//             S = q''·k^T (MFMA), P = exp2(S) (no max subtraction — logits
//             bounded ~25, fp32 exp2 can't overflow), O += P·V (MFMA),
//             l += P·ones (MFMA with constant ones fragment), y = O/l.
// ---------------------------------------------------------------------------

typedef __bf16 bf16;
typedef __attribute__((ext_vector_type(8))) __bf16 bf16x8;
typedef __attribute__((ext_vector_type(4))) float f32x4;

#define MFMA16(a, b, c) __builtin_amdgcn_mfma_f32_16x16x32_bf16(a, b, c, 0, 0, 0)

#if __has_builtin(__builtin_amdgcn_exp2f)
#define EXP2F(x) __builtin_amdgcn_exp2f(x)
#else
#define EXP2F(x) exp2f(x)
#endif

static constexpr int BATCH = 4;
static constexpr int N = 4096;
static constexpr int D = 128;
// fold 1/sqrt(128) and log2(e) into q so softmax is raw exp2
static constexpr float QSCALE = 0.088388347648318447f * 1.4426950408889634f;

// load 8 consecutive fp32 and round to bf16x8 fragment
__device__ inline bf16x8 ld8_f32_bf16(const float* __restrict__ p) {
    f32x4 a = *(const f32x4*)p;
    f32x4 b = *(const f32x4*)(p + 4);
    bf16x8 r;
    r[0] = (bf16)a[0]; r[1] = (bf16)a[1]; r[2] = (bf16)a[2]; r[3] = (bf16)a[3];
    r[4] = (bf16)b[0]; r[5] = (bf16)b[1]; r[6] = (bf16)b[2]; r[7] = (bf16)b[3];
    return r;
}

// ---------------------------------------------------------------------------
// q'' and k projections.  grid 256 x 256 threads; block = 64 rows, wave = 16.
// A = x rows (fp32->bf16), B = W rows (fp32->bf16): W[d][h] is contiguous in h,
// exactly the B-fragment layout (col d = lane&15, k = quad*8+j).
// ---------------------------------------------------------------------------
__global__ __launch_bounds__(256) void proj_qk(const float* __restrict__ x,
                                               const float* __restrict__ Wq,
                                               const float* __restrict__ Wk,
                                               bf16* __restrict__ qw,
                                               bf16* __restrict__ kw) {
    const int lane = threadIdx.x & 63;
    const int w = threadIdx.x >> 6;
    const int l16 = lane & 15;
    const int quad = lane >> 4;
    const int r0 = blockIdx.x * 64 + w * 16;

    bf16x8 a[4];
#pragma unroll
    for (int ks = 0; ks < 4; ks++)
        a[ks] = ld8_f32_bf16(x + (r0 + l16) * D + ks * 32 + quad * 8);

    // q (scaled)
#pragma unroll
    for (int nt = 0; nt < 8; nt++) {
        f32x4 acc = {0.f, 0.f, 0.f, 0.f};
#pragma unroll
        for (int ks = 0; ks < 4; ks++) {
            bf16x8 bw = ld8_f32_bf16(Wq + (nt * 16 + l16) * D + ks * 32 + quad * 8);
            acc = MFMA16(a[ks], bw, acc);
        }
#pragma unroll
        for (int rg = 0; rg < 4; rg++)
            qw[(r0 + quad * 4 + rg) * D + nt * 16 + l16] = (bf16)(acc[rg] * QSCALE);
    }
    // k (unscaled)
#pragma unroll
    for (int nt = 0; nt < 8; nt++) {
        f32x4 acc = {0.f, 0.f, 0.f, 0.f};
#pragma unroll
        for (int ks = 0; ks < 4; ks++) {
            bf16x8 bw = ld8_f32_bf16(Wk + (nt * 16 + l16) * D + ks * 32 + quad * 8);
            acc = MFMA16(a[ks], bw, acc);
        }
#pragma unroll
        for (int rg = 0; rg < 4; rg++)
            kw[(r0 + quad * 4 + rg) * D + nt * 16 + l16] = (bf16)acc[rg];
    }
}

// ---------------------------------------------------------------------------
// v^T projection: vt[b][o][n] = sum_h Wv[o][h] * x[b,n,h].
// A = Wv (m = o), B = x^T (col n = lane&15, k = h contiguous in x row).
// grid 256 (64 cols each) x 256 threads; wave handles 2 m-tiles x 4 n-tiles.
// ---------------------------------------------------------------------------
__global__ __launch_bounds__(256) void proj_vt(const float* __restrict__ x,
                                               const float* __restrict__ Wv,
                                               bf16* __restrict__ vt) {
    const int lane = threadIdx.x & 63;
    const int w = threadIdx.x >> 6;
    const int l16 = lane & 15;
    const int quad = lane >> 4;
    const int n0 = blockIdx.x * 64;       // flat row index into x
    const int b = blockIdx.x >> 6;        // 64 blocks per batch
    const int nin = (blockIdx.x & 63) * 64;

    bf16x8 bx[4][4];
#pragma unroll
    for (int nt = 0; nt < 4; nt++)
#pragma unroll
        for (int ks = 0; ks < 4; ks++)
            bx[nt][ks] = ld8_f32_bf16(x + (n0 + nt * 16 + l16) * D + ks * 32 + quad * 8);

#pragma unroll
    for (int mi = 0; mi < 2; mi++) {
        const int mt = 2 * w + mi;
        bf16x8 aw[4];
#pragma unroll
        for (int ks = 0; ks < 4; ks++)
            aw[ks] = ld8_f32_bf16(Wv + (mt * 16 + l16) * D + ks * 32 + quad * 8);
#pragma unroll
        for (int nt = 0; nt < 4; nt++) {
            f32x4 acc = {0.f, 0.f, 0.f, 0.f};
#pragma unroll
            for (int ks = 0; ks < 4; ks++)
                acc = MFMA16(aw[ks], bx[nt][ks], acc);
#pragma unroll
            for (int rg = 0; rg < 4; rg++)
                vt[b * (D * N) + (mt * 16 + quad * 4 + rg) * N + nin + nt * 16 + l16] =
                    (bf16)acc[rg];
        }
    }
}

// ---------------------------------------------------------------------------
// Flash attention. grid 256 x 256 threads. Block = 64 q rows (16/wave),
// K streamed in 64-key tiles. No barriers (P transpose LDS is wave-private).
// ---------------------------------------------------------------------------
__global__ __launch_bounds__(256) void flash(const bf16* __restrict__ qw,
                                             const bf16* __restrict__ kw,
                                             const bf16* __restrict__ vt,
                                             float* __restrict__ out) {
    // P strip per wave: 16 rows x 64 keys, row padded to 72 bf16 (144B, 16B
    // aligned) to spread LDS banks for ds_read_b128.
    __shared__ __attribute__((aligned(16))) bf16 Ps[4][16][72];

    const int lane = threadIdx.x & 63;
    const int w = threadIdx.x >> 6;
    const int l16 = lane & 15;
    const int quad = lane >> 4;

    // XCD swizzle: consecutive blockIdx round-robin across 8 XCDs; map so each
    // XCD sees one batch -> that batch's K/V (2MB) stays in its 4MB L2.
    const int lo = blockIdx.x & 7;
    const int hi = blockIdx.x >> 3;
    const int batch = lo >> 1;
    const int qblk = hi * 2 + (lo & 1);

    const bf16* __restrict__ qp = qw + batch * (N * D);
    const bf16* __restrict__ kp = kw + batch * (N * D);
    const bf16* __restrict__ vp = vt + batch * (D * N);
    float* __restrict__ yp = out + batch * (N * D);
    const int q0 = qblk * 64 + w * 16;

    // Q A-fragments: row m = l16, k = quad*8 + j (+32*ks). Held all kernel.
    bf16x8 aq[4];
#pragma unroll
    for (int ks = 0; ks < 4; ks++)
        aq[ks] = *(const bf16x8*)(qp + (q0 + l16) * D + ks * 32 + quad * 8);

    // 8 output tiles + 1 row-sum tile (B = ones)
    f32x4 oacc[9];
#pragma unroll
    for (int i = 0; i < 9; i++) oacc[i] = (f32x4){0.f, 0.f, 0.f, 0.f};

    bf16x8 vone;
#pragma unroll
    for (int j = 0; j < 8; j++) vone[j] = (bf16)1.0f;

    for (int kb = 0; kb < N; kb += 64) {
        // K B-fragments: col = key = kb + nt*16 + l16, k = quad*8+j
        bf16x8 bk[4][4];
#pragma unroll
        for (int nt = 0; nt < 4; nt++)
#pragma unroll
            for (int ks = 0; ks < 4; ks++)
                bk[nt][ks] =
                    *(const bf16x8*)(kp + (kb + nt * 16 + l16) * D + ks * 32 + quad * 8);

        // S = q''·k^T  (C layout: row = quad*4+rg, col = l16)
        f32x4 s[4];
#pragma unroll
        for (int nt = 0; nt < 4; nt++) {
            f32x4 acc = {0.f, 0.f, 0.f, 0.f};
#pragma unroll
            for (int ks = 0; ks < 4; ks++) acc = MFMA16(aq[ks], bk[nt][ks], acc);
            s[nt] = acc;
        }

        // P = exp2(S) -> LDS (C layout scatter), bf16
#pragma unroll
        for (int nt = 0; nt < 4; nt++)
#pragma unroll
            for (int rg = 0; rg < 4; rg++)
                Ps[w][quad * 4 + rg][nt * 16 + l16] = (bf16)EXP2F(s[nt][rg]);

        // P back as A-fragments: row m = l16, k = key = quad*8+j (+32*ks2)
        bf16x8 ap[2];
#pragma unroll
        for (int ks2 = 0; ks2 < 2; ks2++)
            ap[ks2] = *(const bf16x8*)&Ps[w][l16][ks2 * 32 + quad * 8];

        // O += P·V   (V^T rows are contiguous in key -> direct B-fragments)
#pragma unroll
        for (int nt8 = 0; nt8 < 8; nt8++) {
#pragma unroll
            for (int ks2 = 0; ks2 < 2; ks2++) {
                bf16x8 bv =
                    *(const bf16x8*)(vp + (nt8 * 16 + l16) * N + kb + ks2 * 32 + quad * 8);
                oacc[nt8] = MFMA16(ap[ks2], bv, oacc[nt8]);
            }
        }
        // l += P·ones
#pragma unroll
        for (int ks2 = 0; ks2 < 2; ks2++) oacc[8] = MFMA16(ap[ks2], vone, oacc[8]);
    }

    // epilogue: y = O / l   (l replicated across all 16 cols of tile 8)
#pragma unroll
    for (int rg = 0; rg < 4; rg++) {
        const float rl = 1.0f / oacc[8][rg];
#pragma unroll
        for (int nt8 = 0; nt8 < 8; nt8++)
            yp[(q0 + quad * 4 + rg) * D + nt8 * 16 + l16] = oacc[nt8][rg] * rl;
    }
}

// ---------------------------------------------------------------------------
extern "C" void kernel_launch(void* const* d_in, const int* in_sizes, int n_in,
                              void* d_out, int out_size, void* d_ws, size_t ws_size,
                              hipStream_t stream) {
    const float* x = (const float*)d_in[0];
    const float* Wq = (const float*)d_in[1];
    const float* Wk = (const float*)d_in[2];
    const float* Wv = (const float*)d_in[3];
    float* y = (float*)d_out;

    bf16* qw = (bf16*)d_ws;                    // [B*N][128] bf16 : 4MB
    bf16* kw = qw + (size_t)BATCH * N * D;     // [B*N][128] bf16 : 4MB
    bf16* vtw = kw + (size_t)BATCH * N * D;    // [B][128][N] bf16: 4MB

    proj_qk<<<256, 256, 0, stream>>>(x, Wq, Wk, qw, kw);
    proj_vt<<<256, 256, 0, stream>>>(x, Wv, vtw);
    flash<<<256, 256, 0, stream>>>(qw, kw, vtw, y);
}

// Round 2
// 321.281 us; speedup vs baseline: 1.4146x; 1.4146x over previous
//
#include <hip/hip_runtime.h>

// ---------------------------------------------------------------------------
// Attention: y = softmax( (xWq^T)(xWk^T)^T / sqrt(128) ) (xWv^T)
// B=4, N=4096, H=OUT=128. fp32 I/O, bf16 MFMA compute.
//
// R2: flash is latency-bound (occupancy 11.7% = 1 wave/SIMD). Add 4-way
// key-split per q-tile (in-block, LDS combine; exact since softmax partials
// are plain sums without max-subtraction) -> 16 waves/CU, and batch V loads.
// ---------------------------------------------------------------------------

typedef __bf16 bf16;
typedef __attribute__((ext_vector_type(8))) __bf16 bf16x8;
typedef __attribute__((ext_vector_type(4))) float f32x4;

#define MFMA16(a, b, c) __builtin_amdgcn_mfma_f32_16x16x32_bf16(a, b, c, 0, 0, 0)

#if __has_builtin(__builtin_amdgcn_exp2f)
#define EXP2F(x) __builtin_amdgcn_exp2f(x)
#else
#define EXP2F(x) exp2f(x)
#endif

static constexpr int BATCH = 4;
static constexpr int N = 4096;
static constexpr int D = 128;
// fold 1/sqrt(128) and log2(e) into q so softmax is raw exp2
static constexpr float QSCALE = 0.088388347648318447f * 1.4426950408889634f;

__device__ inline bf16x8 ld8_f32_bf16(const float* __restrict__ p) {
    f32x4 a = *(const f32x4*)p;
    f32x4 b = *(const f32x4*)(p + 4);
    bf16x8 r;
    r[0] = (bf16)a[0]; r[1] = (bf16)a[1]; r[2] = (bf16)a[2]; r[3] = (bf16)a[3];
    r[4] = (bf16)b[0]; r[5] = (bf16)b[1]; r[6] = (bf16)b[2]; r[7] = (bf16)b[3];
    return r;
}

// ---------------------------------------------------------------------------
// q'' / k projection. grid 512: even blocks -> q (scaled), odd -> k.
// Block = 64 rows, wave = 16 rows, 8 out-tiles each.
// ---------------------------------------------------------------------------
__global__ __launch_bounds__(256) void proj_qk(const float* __restrict__ x,
                                               const float* __restrict__ Wq,
                                               const float* __restrict__ Wk,
                                               bf16* __restrict__ qw,
                                               bf16* __restrict__ kw) {
    const int lane = threadIdx.x & 63;
    const int w = threadIdx.x >> 6;
    const int l16 = lane & 15;
    const int quad = lane >> 4;
    const int half = blockIdx.x & 1;
    const int rb = blockIdx.x >> 1;
    const float* __restrict__ W = half ? Wk : Wq;
    bf16* __restrict__ outp = half ? kw : qw;
    const float scale = half ? 1.0f : QSCALE;
    const int r0 = rb * 64 + w * 16;

    bf16x8 a[4];
#pragma unroll
    for (int ks = 0; ks < 4; ks++)
        a[ks] = ld8_f32_bf16(x + (r0 + l16) * D + ks * 32 + quad * 8);

#pragma unroll
    for (int nt = 0; nt < 8; nt++) {
        f32x4 acc = {0.f, 0.f, 0.f, 0.f};
#pragma unroll
        for (int ks = 0; ks < 4; ks++) {
            bf16x8 bw = ld8_f32_bf16(W + (nt * 16 + l16) * D + ks * 32 + quad * 8);
            acc = MFMA16(a[ks], bw, acc);
        }
#pragma unroll
        for (int rg = 0; rg < 4; rg++)
            outp[(r0 + quad * 4 + rg) * D + nt * 16 + l16] = (bf16)(acc[rg] * scale);
    }
}

// ---------------------------------------------------------------------------
// v^T projection: vt[b][o][n]. grid 512: (n-block 0..255) x (m-half 0..1);
// one m-tile per wave.
// ---------------------------------------------------------------------------
__global__ __launch_bounds__(256) void proj_vt(const float* __restrict__ x,
                                               const float* __restrict__ Wv,
                                               bf16* __restrict__ vt) {
    const int lane = threadIdx.x & 63;
    const int w = threadIdx.x >> 6;
    const int l16 = lane & 15;
    const int quad = lane >> 4;
    const int half = blockIdx.x & 1;
    const int nb = blockIdx.x >> 1;
    const int n0 = nb * 64;
    const int b = nb >> 6;
    const int nin = (nb & 63) * 64;
    const int mt = half * 4 + w;

    bf16x8 bx[4][4];
#pragma unroll
    for (int nt = 0; nt < 4; nt++)
#pragma unroll
        for (int ks = 0; ks < 4; ks++)
            bx[nt][ks] = ld8_f32_bf16(x + (n0 + nt * 16 + l16) * D + ks * 32 + quad * 8);

    bf16x8 aw[4];
#pragma unroll
    for (int ks = 0; ks < 4; ks++)
        aw[ks] = ld8_f32_bf16(Wv + (mt * 16 + l16) * D + ks * 32 + quad * 8);
#pragma unroll
    for (int nt = 0; nt < 4; nt++) {
        f32x4 acc = {0.f, 0.f, 0.f, 0.f};
#pragma unroll
        for (int ks = 0; ks < 4; ks++)
            acc = MFMA16(aw[ks], bx[nt][ks], acc);
#pragma unroll
        for (int rg = 0; rg < 4; rg++)
            vt[b * (D * N) + (mt * 16 + quad * 4 + rg) * N + nin + nt * 16 + l16] =
                (bf16)acc[rg];
    }
}

// ---------------------------------------------------------------------------
// Flash attention with in-block 4-way key split.
// grid 512 x 512 threads. Block = 32 q rows = 2 q-tiles; 8 waves =
// (qw in {0,1}) x (ks in {0..3}); wave handles 16 q rows x 1024 keys
// (16 iters of KTILE=64). Partials (plain sums - no max subtraction) are
// combined through LDS at the end.
// ---------------------------------------------------------------------------
__global__ __launch_bounds__(512, 4) void flash(const bf16* __restrict__ qw_,
                                                const bf16* __restrict__ kw_,
                                                const bf16* __restrict__ vt,
                                                float* __restrict__ out) {
    // Aliased LDS: during main loop, per-wave P strips (8 x 16 x 72 bf16 =
    // 18432 B); after first barrier, partial-O buffer (3 x 2 x 16 x 148 f32
    // = 56832 B). Row stride 148: 4-row stride = 592 dw = 16 mod 32 -> 2-way.
    __shared__ __attribute__((aligned(16))) unsigned char smem[56832];

    const int lane = threadIdx.x & 63;
    const int w = threadIdx.x >> 6;   // 0..7
    const int l16 = lane & 15;
    const int quad = lane >> 4;
    const int qw_i = w & 1;           // which q-tile of the block
    const int ks_i = w >> 1;          // key-split index 0..3

    // XCD swizzle: 8 consecutive blocks round-robin the 8 XCDs; 2 XCDs per
    // batch so each XCD's L2 holds one batch's K+V (2MB < 4MB).
    const int lo = blockIdx.x & 7;
    const int hi = blockIdx.x >> 3;          // 0..63
    const int batch = lo >> 1;
    const int qpos = hi * 2 + (lo & 1);      // 0..127

    const bf16* __restrict__ qp = qw_ + batch * (N * D);
    const bf16* __restrict__ kp = kw_ + batch * (N * D);
    const bf16* __restrict__ vp = vt + batch * (D * N);
    float* __restrict__ yp = out + batch * (N * D);
    const int q0 = qpos * 32 + qw_i * 16;

    bf16* __restrict__ Ps = (bf16*)smem + w * (16 * 72);

    // Q A-fragments, held all kernel
    bf16x8 aq[4];
#pragma unroll
    for (int ks = 0; ks < 4; ks++)
        aq[ks] = *(const bf16x8*)(qp + (q0 + l16) * D + ks * 32 + quad * 8);

    f32x4 oacc[9];
#pragma unroll
    for (int i = 0; i < 9; i++) oacc[i] = (f32x4){0.f, 0.f, 0.f, 0.f};

    bf16x8 vone;
#pragma unroll
    for (int j = 0; j < 8; j++) vone[j] = (bf16)1.0f;

    const int kb0 = ks_i * (N / 4);
    for (int it = 0; it < 16; it++) {
        const int kb = kb0 + it * 64;

        // K B-fragments + S MFMAs
        bf16x8 bk[4][4];
#pragma unroll
        for (int nt = 0; nt < 4; nt++)
#pragma unroll
            for (int ks = 0; ks < 4; ks++)
                bk[nt][ks] =
                    *(const bf16x8*)(kp + (kb + nt * 16 + l16) * D + ks * 32 + quad * 8);

        f32x4 s[4];
#pragma unroll
        for (int nt = 0; nt < 4; nt++) {
            f32x4 acc = {0.f, 0.f, 0.f, 0.f};
#pragma unroll
            for (int ks = 0; ks < 4; ks++) acc = MFMA16(aq[ks], bk[nt][ks], acc);
            s[nt] = acc;
        }

        // P = exp2(S) -> wave-private LDS strip -> A-fragments
#pragma unroll
        for (int nt = 0; nt < 4; nt++)
#pragma unroll
            for (int rg = 0; rg < 4; rg++)
                Ps[(quad * 4 + rg) * 72 + nt * 16 + l16] = (bf16)EXP2F(s[nt][rg]);

        bf16x8 ap[2];
#pragma unroll
        for (int ks2 = 0; ks2 < 2; ks2++)
            ap[ks2] = *(const bf16x8*)&Ps[l16 * 72 + ks2 * 32 + quad * 8];

        // O += P.V, V loads batched in groups of 8
#pragma unroll
        for (int h = 0; h < 2; h++) {
            bf16x8 bv[8];
#pragma unroll
            for (int i = 0; i < 4; i++)
#pragma unroll
                for (int ks2 = 0; ks2 < 2; ks2++)
                    bv[i * 2 + ks2] = *(const bf16x8*)(vp + ((h * 4 + i) * 16 + l16) * N +
                                                       kb + ks2 * 32 + quad * 8);
#pragma unroll
            for (int i = 0; i < 4; i++)
#pragma unroll
                for (int ks2 = 0; ks2 < 2; ks2++)
                    oacc[h * 4 + i] = MFMA16(ap[ks2], bv[i * 2 + ks2], oacc[h * 4 + i]);
        }
        // l += P.ones
#pragma unroll
        for (int ks2 = 0; ks2 < 2; ks2++) oacc[8] = MFMA16(ap[ks2], vone, oacc[8]);
    }

    // ---- combine the 4 key-split partials through LDS ----
    __syncthreads();  // everyone done with Ps strips
    float* __restrict__ Rs = (float*)smem;  // [3][2][16][148]
    if (ks_i > 0) {
        float* __restrict__ dst = Rs + ((ks_i - 1) * 2 + qw_i) * (16 * 148);
#pragma unroll
        for (int t = 0; t < 9; t++)
#pragma unroll
            for (int rg = 0; rg < 4; rg++)
                dst[(quad * 4 + rg) * 148 + t * 16 + l16] = oacc[t][rg];
    }
    __syncthreads();
    if (ks_i == 0) {
#pragma unroll
        for (int sIdx = 0; sIdx < 3; sIdx++) {
            const float* __restrict__ src = Rs + (sIdx * 2 + qw_i) * (16 * 148);
#pragma unroll
            for (int t = 0; t < 9; t++)
#pragma unroll
                for (int rg = 0; rg < 4; rg++)
                    oacc[t][rg] += src[(quad * 4 + rg) * 148 + t * 16 + l16];
        }
        // epilogue: y = O / l (l replicated across the 16 cols of tile 8)
#pragma unroll
        for (int rg = 0; rg < 4; rg++) {
            const float rl = 1.0f / oacc[8][rg];
#pragma unroll
            for (int t = 0; t < 8; t++)
                yp[(q0 + quad * 4 + rg) * D + t * 16 + l16] = oacc[t][rg] * rl;
        }
    }
}

// ---------------------------------------------------------------------------
extern "C" void kernel_launch(void* const* d_in, const int* in_sizes, int n_in,
                              void* d_out, int out_size, void* d_ws, size_t ws_size,
                              hipStream_t stream) {
    const float* x = (const float*)d_in[0];
    const float* Wq = (const float*)d_in[1];
    const float* Wk = (const float*)d_in[2];
    const float* Wv = (const float*)d_in[3];
    float* y = (float*)d_out;

    bf16* qw = (bf16*)d_ws;                    // [B*N][128] bf16 : 4MB
    bf16* kw = qw + (size_t)BATCH * N * D;     // [B*N][128] bf16 : 4MB
    bf16* vtw = kw + (size_t)BATCH * N * D;    // [B][128][N] bf16: 4MB

    proj_qk<<<512, 256, 0, stream>>>(x, Wq, Wk, qw, kw);
    proj_vt<<<512, 256, 0, stream>>>(x, Wv, vtw);
    flash<<<512, 512, 0, stream>>>(qw, kw, vtw, y);
}

// Round 3
// 232.442 us; speedup vs baseline: 1.9553x; 1.3822x over previous
//
#include <hip/hip_runtime.h>

// ---------------------------------------------------------------------------
// Attention: y = softmax( (xWq^T)(xWk^T)^T / sqrt(128) ) (xWv^T)
// B=4, N=4096, H=OUT=128. fp32 I/O, bf16 MFMA compute.
//
// R3: r2 was strangled at VGPR=64 (launch-bounds too tight -> serialized
// vmcnt(0) loads) and had a 61us L2 floor (each wave privately gathered its
// K/V tiles for only 16 q-rows). Restructure:
//   proj_all : one kernel writes Q/K/V in PRE-SWIZZLED MFMA-fragment order
//              (all flash loads become coalesced 1KB dwordx4).
//   flash    : 512 blocks x 512 thr; block = 256 q-rows (8 waves x 32 rows),
//              key-split S=8 across blocks; all waves of a block read the SAME
//              key tile each iter (L1/L2-hot). Partial (O,l) are plain sums
//              (no max subtraction) -> exact split; partials to ws.
//   norm     : sum 8 partials, divide by l, write fp32 y.
// ---------------------------------------------------------------------------

typedef __bf16 bf16;
typedef __attribute__((ext_vector_type(8))) __bf16 bf16x8;
typedef __attribute__((ext_vector_type(4))) float f32x4;

#define MFMA16(a, b, c) __builtin_amdgcn_mfma_f32_16x16x32_bf16(a, b, c, 0, 0, 0)

#if __has_builtin(__builtin_amdgcn_exp2f)
#define EXP2F(x) __builtin_amdgcn_exp2f(x)
#else
#define EXP2F(x) exp2f(x)
#endif

static constexpr int BATCH = 4;
static constexpr int N = 4096;
static constexpr int D = 128;
static constexpr int SPLITS = 8;
static constexpr int ROWS = BATCH * N;          // 16384
// fold 1/sqrt(128) and log2(e) into q so softmax is raw exp2
static constexpr float QSCALE = 0.088388347648318447f * 1.4426950408889634f;

__device__ inline bf16x8 ld8_f32_bf16(const float* __restrict__ p) {
    f32x4 a = *(const f32x4*)p;
    f32x4 b = *(const f32x4*)(p + 4);
    bf16x8 r;
    r[0] = (bf16)a[0]; r[1] = (bf16)a[1]; r[2] = (bf16)a[2]; r[3] = (bf16)a[3];
    r[4] = (bf16)b[0]; r[5] = (bf16)b[1]; r[6] = (bf16)b[2]; r[7] = (bf16)b[3];
    return r;
}

// Fragment layouts (16x16x32 bf16; lane = quad*16+l16):
//  qf/kf: elem (tile, row, d):  [tile][ks=d>>5][lane: quad=(d&31)>>3,l16=row][j=d&7]
//         flat = ((tile*4+ks)*64 + lane)*8 + j      (1KB per (tile,ks), lane-major)
//  vf:    elem (o, key): vg=key>>5 (+128*batch);
//         flat = (((vg)*8 + (o>>4))*64 + ((key&31)>>3)*16 + (o&15))*8 + (key&7)

// ---------------------------------------------------------------------------
// proj_all: grid 512 x 256. Block = 32 tokens (2 tiles). Wave w: token-tile
// (w&1); w<2 -> Q else K (8 d-tiles); plus 4 V out-tiles (range by w>>1).
// ---------------------------------------------------------------------------
__global__ __launch_bounds__(256) void proj_all(const float* __restrict__ x,
                                                const float* __restrict__ Wq,
                                                const float* __restrict__ Wk,
                                                const float* __restrict__ Wv,
                                                bf16* __restrict__ qf,
                                                bf16* __restrict__ kf,
                                                bf16* __restrict__ vf) {
    const int lane = threadIdx.x & 63;
    const int w = threadIdx.x >> 6;
    const int l16 = lane & 15;
    const int quad = lane >> 4;
    const int t0 = blockIdx.x * 32;
    const int tt = w & 1;
    const int tok_base = t0 + tt * 16;

    // x A/B-fragments for this token tile (A and B lane layouts are identical)
    bf16x8 xa[4];
#pragma unroll
    for (int ks = 0; ks < 4; ks++)
        xa[ks] = ld8_f32_bf16(x + (tok_base + l16) * D + ks * 32 + quad * 8);

    // ---- Q or K path ----
    const float* __restrict__ W = (w < 2) ? Wq : Wk;
    bf16* __restrict__ outp = (w < 2) ? qf : kf;
    const float scale = (w < 2) ? QSCALE : 1.0f;
    const int tile = t0 / 16 + tt;
#pragma unroll
    for (int nt = 0; nt < 8; nt++) {
        f32x4 acc = {0.f, 0.f, 0.f, 0.f};
#pragma unroll
        for (int ks = 0; ks < 4; ks++) {
            bf16x8 bw = ld8_f32_bf16(W + (nt * 16 + l16) * D + ks * 32 + quad * 8);
            acc = MFMA16(xa[ks], bw, acc);
        }
        // C[row=quad*4+rg][d=nt*16+l16] -> fragment layout
        const int d = nt * 16 + l16;
        const int base = ((tile * 4 + (d >> 5)) * 64 + ((d & 31) >> 3) * 16) * 8 + (d & 7);
#pragma unroll
        for (int rg = 0; rg < 4; rg++)
            outp[base + (quad * 4 + rg) * 8] = (bf16)(acc[rg] * scale);
    }

    // ---- V path: C[o][token] = Wv(A) x x(B) ----
    const int batch = tok_base >> 12;
    const int key32 = tok_base & 31;              // 0 or 16
    const int vg = batch * 128 + ((tok_base & (N - 1)) >> 5);
    const int colk = key32 + l16;                 // key mod 32 for this lane
    const int quadv = colk >> 3, jv = colk & 7;
    const int mt0 = (w >> 1) * 4;
#pragma unroll
    for (int mi = 0; mi < 4; mi++) {
        const int mt = mt0 + mi;
        f32x4 acc = {0.f, 0.f, 0.f, 0.f};
#pragma unroll
        for (int ks = 0; ks < 4; ks++) {
            bf16x8 aw = ld8_f32_bf16(Wv + (mt * 16 + l16) * D + ks * 32 + quad * 8);
            acc = MFMA16(aw, xa[ks], acc);
        }
#pragma unroll
        for (int rg = 0; rg < 4; rg++) {
            const int o = mt * 16 + quad * 4 + rg;
            vf[(((size_t)vg * 8 + (o >> 4)) * 64 + quadv * 16 + (o & 15)) * 8 + jv] =
                (bf16)acc[rg];
        }
    }
}

// ---------------------------------------------------------------------------
// flash: grid 512 x 512. block = (qgroup g = bid>>3: 256 q-rows) x (split
// s = bid&7: keys [s*512, +512), 8 iters of 64). Wave = 32 q-rows (2 tiles).
// All 8 waves consume the same key tile -> L1/L2 reuse. Partials (O bf16,
// l f32) written to ws; no atomics, no barriers.
// ---------------------------------------------------------------------------
__global__ __launch_bounds__(512, 4) void flash(const bf16* __restrict__ qf,
                                                const bf16* __restrict__ kf,
                                                const bf16* __restrict__ vf,
                                                bf16* __restrict__ part,
                                                float* __restrict__ lpart) {
    __shared__ __attribute__((aligned(16))) bf16 Ps[8][2][16][72];

    const int lane = threadIdx.x & 63;
    const int w = threadIdx.x >> 6;
    const int l16 = lane & 15;
    const int quad = lane >> 4;

    const int s = blockIdx.x & 7;       // split (also XCD id -> key-slice L2 locality)
    const int g = blockIdx.x >> 3;      // q-group 0..63
    const int q0 = g * 256 + w * 32;    // flat q row of this wave's tile 0
    const int batch = q0 >> 12;
    const int qt0 = q0 >> 4;            // flat q tile
    const int kb0 = s * (N / SPLITS);

    bf16x8 vone;
#pragma unroll
    for (int j = 0; j < 8; j++) vone[j] = (bf16)1.0f;

    f32x4 oacc[2][9];
#pragma unroll
    for (int qt = 0; qt < 2; qt++)
#pragma unroll
        for (int i = 0; i < 9; i++) oacc[qt][i] = (f32x4){0.f, 0.f, 0.f, 0.f};

    for (int it = 0; it < N / SPLITS / 64; it++) {
        const int kb = kb0 + it * 64;
        const int ktile = batch * 256 + (kb >> 4);

        // ---- S = q''.k^T : ks-outer (sv[2][4] live, aq transient) ----
        f32x4 sv[2][4];
#pragma unroll
        for (int qt = 0; qt < 2; qt++)
#pragma unroll
            for (int nt = 0; nt < 4; nt++) sv[qt][nt] = (f32x4){0.f, 0.f, 0.f, 0.f};
#pragma unroll
        for (int ks = 0; ks < 4; ks++) {
            bf16x8 aq0 = *(const bf16x8*)(qf + (((qt0 + 0) * 4 + ks) * 64 + lane) * 8);
            bf16x8 aq1 = *(const bf16x8*)(qf + (((qt0 + 1) * 4 + ks) * 64 + lane) * 8);
#pragma unroll
            for (int nt = 0; nt < 4; nt++) {
                bf16x8 bk = *(const bf16x8*)(kf + (((ktile + nt) * 4 + ks) * 64 + lane) * 8);
                sv[0][nt] = MFMA16(aq0, bk, sv[0][nt]);
                sv[1][nt] = MFMA16(aq1, bk, sv[1][nt]);
            }
        }

        // ---- P = exp2(S) -> wave-private LDS strips (C-layout scatter) ----
#pragma unroll
        for (int qt = 0; qt < 2; qt++)
#pragma unroll
            for (int nt = 0; nt < 4; nt++)
#pragma unroll
                for (int rg = 0; rg < 4; rg++)
                    Ps[w][qt][quad * 4 + rg][nt * 16 + l16] = (bf16)EXP2F(sv[qt][nt][rg]);

        // ---- P back as A-fragments ----
        bf16x8 ap[2][2];
#pragma unroll
        for (int qt = 0; qt < 2; qt++)
#pragma unroll
            for (int ks2 = 0; ks2 < 2; ks2++)
                ap[qt][ks2] = *(const bf16x8*)&Ps[w][qt][l16][ks2 * 32 + quad * 8];

        // ---- O += P.V  (V fragments shared across both q-tiles) ----
        const int vg = batch * 128 + (kb >> 5);
#pragma unroll
        for (int ot = 0; ot < 8; ot++) {
            bf16x8 bv0 = *(const bf16x8*)(vf + (((size_t)(vg + 0) * 8 + ot) * 64 + lane) * 8);
            bf16x8 bv1 = *(const bf16x8*)(vf + (((size_t)(vg + 1) * 8 + ot) * 64 + lane) * 8);
            oacc[0][ot] = MFMA16(ap[0][0], bv0, oacc[0][ot]);
            oacc[0][ot] = MFMA16(ap[0][1], bv1, oacc[0][ot]);
            oacc[1][ot] = MFMA16(ap[1][0], bv0, oacc[1][ot]);
            oacc[1][ot] = MFMA16(ap[1][1], bv1, oacc[1][ot]);
        }
        // ---- l += P.ones ----
#pragma unroll
        for (int qt = 0; qt < 2; qt++) {
            oacc[qt][8] = MFMA16(ap[qt][0], vone, oacc[qt][8]);
            oacc[qt][8] = MFMA16(ap[qt][1], vone, oacc[qt][8]);
        }
    }

    // ---- epilogue: write partials ----
#pragma unroll
    for (int qt = 0; qt < 2; qt++) {
#pragma unroll
        for (int rg = 0; rg < 4; rg++) {
            const int row = q0 + qt * 16 + quad * 4 + rg;
#pragma unroll
            for (int ot = 0; ot < 8; ot++)
                part[((size_t)s * ROWS + row) * D + ot * 16 + l16] =
                    (bf16)oacc[qt][ot][rg];
        }
        if (l16 == 0) {
#pragma unroll
            for (int rg = 0; rg < 4; rg++)
                lpart[s * ROWS + q0 + qt * 16 + quad * 4 + rg] = oacc[qt][8][rg];
        }
    }
}

// ---------------------------------------------------------------------------
// norm_combine: grid 512 x 256. Wave = 8 rows; lane = (row 8, col-chunk 16).
// y[row][c..c+15] = sum_s O_s / sum_s l_s
// ---------------------------------------------------------------------------
__global__ __launch_bounds__(256) void norm_combine(const bf16* __restrict__ part,
                                                    const float* __restrict__ lpart,
                                                    float* __restrict__ out) {
    const int lane = threadIdx.x & 63;
    const int w = threadIdx.x >> 6;
    const int row = blockIdx.x * 32 + w * 8 + (lane >> 3);
    const int c = (lane & 7) * 16;

    float acc[16];
#pragma unroll
    for (int i = 0; i < 16; i++) acc[i] = 0.f;
    float L = 0.f;

#pragma unroll
    for (int s = 0; s < SPLITS; s++) {
        const bf16* __restrict__ p = part + ((size_t)s * ROWS + row) * D + c;
        bf16x8 a = *(const bf16x8*)p;
        bf16x8 b = *(const bf16x8*)(p + 8);
#pragma unroll
        for (int i = 0; i < 8; i++) {
            acc[i] += (float)a[i];
            acc[8 + i] += (float)b[i];
        }
        L += lpart[s * ROWS + row];
    }
    const float rl = 1.0f / L;
    float* __restrict__ o = out + (size_t)row * D + c;
#pragma unroll
    for (int k = 0; k < 4; k++) {
        f32x4 v = {acc[k * 4 + 0] * rl, acc[k * 4 + 1] * rl, acc[k * 4 + 2] * rl,
                   acc[k * 4 + 3] * rl};
        *(f32x4*)(o + k * 4) = v;
    }
}

// ---------------------------------------------------------------------------
extern "C" void kernel_launch(void* const* d_in, const int* in_sizes, int n_in,
                              void* d_out, int out_size, void* d_ws, size_t ws_size,
                              hipStream_t stream) {
    const float* x = (const float*)d_in[0];
    const float* Wq = (const float*)d_in[1];
    const float* Wk = (const float*)d_in[2];
    const float* Wv = (const float*)d_in[3];
    float* y = (float*)d_out;

    // ws layout (bytes): qf 4MB | kf 4MB | vf 4MB | part 33.5MB | lpart 0.5MB
    bf16* qf = (bf16*)d_ws;
    bf16* kf = qf + (size_t)ROWS * D;
    bf16* vf = kf + (size_t)ROWS * D;
    bf16* part = vf + (size_t)ROWS * D;
    float* lpart = (float*)(part + (size_t)SPLITS * ROWS * D);

    proj_all<<<512, 256, 0, stream>>>(x, Wq, Wk, Wv, qf, kf, vf);
    flash<<<512, 512, 0, stream>>>(qf, kf, vf, part, lpart);
    norm_combine<<<512, 256, 0, stream>>>(part, lpart, y);
}

// Round 4
// 185.241 us; speedup vs baseline: 2.4535x; 1.2548x over previous
//
#include <hip/hip_runtime.h>

// ---------------------------------------------------------------------------
// Attention: y = softmax( (xWq^T)(xWk^T)^T / sqrt(128) ) (xWv^T)
// B=4, N=4096, H=OUT=128. fp32 I/O, bf16 MFMA compute.
//
// R4: r3 was fabric-traffic-bound (454MB: Q re-fetched every iter because aq
// loads sat inside the k-loop; 33.5MB bf16 partials amplified to 205MB of
// sector-RMW writes + re-read by norm_combine). Fix:
//   - Q hoisted to registers (1 q-tile/wave, live set ~110 VGPR <= 128).
//   - In-block key-split combine through LDS (fp32), y written directly.
//     No partials buffer, no norm kernel. Exact: partials are plain sums
//     (no max subtraction; logits bounded so exp2 can't overflow).
//   - All Q/K/V loads stay coalesced 1KB dwordx4 via pre-swizzled fragment
//     layouts written by proj_all.
// ---------------------------------------------------------------------------

typedef __bf16 bf16;
typedef __attribute__((ext_vector_type(8))) __bf16 bf16x8;
typedef __attribute__((ext_vector_type(4))) float f32x4;

#define MFMA16(a, b, c) __builtin_amdgcn_mfma_f32_16x16x32_bf16(a, b, c, 0, 0, 0)

#if __has_builtin(__builtin_amdgcn_exp2f)
#define EXP2F(x) __builtin_amdgcn_exp2f(x)
#else
#define EXP2F(x) exp2f(x)
#endif

static constexpr int BATCH = 4;
static constexpr int N = 4096;
static constexpr int D = 128;
static constexpr int ROWS = BATCH * N;  // 16384
// fold 1/sqrt(128) and log2(e) into q so softmax is raw exp2
static constexpr float QSCALE = 0.088388347648318447f * 1.4426950408889634f;

__device__ inline bf16x8 ld8_f32_bf16(const float* __restrict__ p) {
    f32x4 a = *(const f32x4*)p;
    f32x4 b = *(const f32x4*)(p + 4);
    bf16x8 r;
    r[0] = (bf16)a[0]; r[1] = (bf16)a[1]; r[2] = (bf16)a[2]; r[3] = (bf16)a[3];
    r[4] = (bf16)b[0]; r[5] = (bf16)b[1]; r[6] = (bf16)b[2]; r[7] = (bf16)b[3];
    return r;
}

// Fragment layouts (16x16x32 bf16; lane = quad*16+l16):
//  qf/kf: elem (tile, row, d): flat = ((tile*4 + (d>>5))*64 + ((d&31)>>3)*16
//         + row)*8 + (d&7)   -- 1KB per (tile,ks), lane-major.
//  vf:    elem (o, key): vg = batch*128 + (key_in_batch>>5);
//         flat = ((vg*8 + (o>>4))*64 + ((key&31)>>3)*16 + (o&15))*8 + (key&7)

// ---------------------------------------------------------------------------
// proj_all: grid 512 x 256. Block = 32 tokens (2 tiles). Wave w: token-tile
// (w&1); w<2 -> Q else K (8 d-tiles); plus 4 V out-tiles (range by w>>1).
// ---------------------------------------------------------------------------
__global__ __launch_bounds__(256) void proj_all(const float* __restrict__ x,
                                                const float* __restrict__ Wq,
                                                const float* __restrict__ Wk,
                                                const float* __restrict__ Wv,
                                                bf16* __restrict__ qf,
                                                bf16* __restrict__ kf,
                                                bf16* __restrict__ vf) {
    const int lane = threadIdx.x & 63;
    const int w = threadIdx.x >> 6;
    const int l16 = lane & 15;
    const int quad = lane >> 4;
    const int t0 = blockIdx.x * 32;
    const int tt = w & 1;
    const int tok_base = t0 + tt * 16;

    bf16x8 xa[4];
#pragma unroll
    for (int ks = 0; ks < 4; ks++)
        xa[ks] = ld8_f32_bf16(x + (tok_base + l16) * D + ks * 32 + quad * 8);

    // ---- Q or K path ----
    const float* __restrict__ W = (w < 2) ? Wq : Wk;
    bf16* __restrict__ outp = (w < 2) ? qf : kf;
    const float scale = (w < 2) ? QSCALE : 1.0f;
    const int tile = t0 / 16 + tt;
#pragma unroll
    for (int nt = 0; nt < 8; nt++) {
        f32x4 acc = {0.f, 0.f, 0.f, 0.f};
#pragma unroll
        for (int ks = 0; ks < 4; ks++) {
            bf16x8 bw = ld8_f32_bf16(W + (nt * 16 + l16) * D + ks * 32 + quad * 8);
            acc = MFMA16(xa[ks], bw, acc);
        }
        const int d = nt * 16 + l16;
        const int base = ((tile * 4 + (d >> 5)) * 64 + ((d & 31) >> 3) * 16) * 8 + (d & 7);
#pragma unroll
        for (int rg = 0; rg < 4; rg++)
            outp[base + (quad * 4 + rg) * 8] = (bf16)(acc[rg] * scale);
    }

    // ---- V path: C[o][token] = Wv(A) x x(B) ----
    const int batch = tok_base >> 12;
    const int key32 = tok_base & 31;  // 0 or 16
    const int vg = batch * 128 + ((tok_base & (N - 1)) >> 5);
    const int colk = key32 + l16;
    const int quadv = colk >> 3, jv = colk & 7;
    const int mt0 = (w >> 1) * 4;
#pragma unroll
    for (int mi = 0; mi < 4; mi++) {
        const int mt = mt0 + mi;
        f32x4 acc = {0.f, 0.f, 0.f, 0.f};
#pragma unroll
        for (int ks = 0; ks < 4; ks++) {
            bf16x8 aw = ld8_f32_bf16(Wv + (mt * 16 + l16) * D + ks * 32 + quad * 8);
            acc = MFMA16(aw, xa[ks], acc);
        }
#pragma unroll
        for (int rg = 0; rg < 4; rg++) {
            const int o = mt * 16 + quad * 4 + rg;
            vf[(((size_t)vg * 8 + (o >> 4)) * 64 + quadv * 16 + (o & 15)) * 8 + jv] =
                (bf16)acc[rg];
        }
    }
}

// ---------------------------------------------------------------------------
// flash: grid 512 x 512. Block = 2 q-tiles (32 rows) x 4 key-splits.
// Wave (qw_i = w&1, ks_i = w>>2? no: w>>1): handles q-tile qw_i over keys
// [ks_i*1024, +1024), 16 iters of 64. Q held in registers. fp32 split
// combine through LDS at the end; y written directly. Batch-pinned XCD
// swizzle keeps each XCD's K+V (2MB) L2-resident.
// ---------------------------------------------------------------------------
__global__ __launch_bounds__(512, 4) void flash(const bf16* __restrict__ qf,
                                                const bf16* __restrict__ kf,
                                                const bf16* __restrict__ vf,
                                                float* __restrict__ out) {
    // Alias: main loop uses Ps strips (8 x 16x72 bf16 = 18432B); after the
    // barrier the same memory is Rs[3][2][16][148] f32 = 56832B.
    __shared__ __attribute__((aligned(16))) unsigned char smem[56832];

    const int lane = threadIdx.x & 63;
    const int w = threadIdx.x >> 6;  // 0..7
    const int l16 = lane & 15;
    const int quad = lane >> 4;
    const int qw_i = w & 1;   // q-tile within block
    const int ks_i = w >> 1;  // key split 0..3

    // XCD swizzle: bid%8 = XCD; 2 XCDs per batch.
    const int lo = blockIdx.x & 7;
    const int hi = blockIdx.x >> 3;          // 0..63
    const int batch = lo >> 1;
    const int qpair = hi * 2 + (lo & 1);     // 0..127
    const int qt = batch * 256 + qpair * 2 + qw_i;  // global q-tile

    bf16* __restrict__ Ps = (bf16*)smem + w * (16 * 72);

    // Q A-fragments in registers for the whole kernel (the r3 bug fix).
    bf16x8 aq[4];
#pragma unroll
    for (int ks = 0; ks < 4; ks++)
        aq[ks] = *(const bf16x8*)(qf + (((size_t)qt * 4 + ks) * 64 + lane) * 8);

    f32x4 oacc[9];
#pragma unroll
    for (int i = 0; i < 9; i++) oacc[i] = (f32x4){0.f, 0.f, 0.f, 0.f};

    bf16x8 vone;
#pragma unroll
    for (int j = 0; j < 8; j++) vone[j] = (bf16)1.0f;

    const int kb0 = ks_i * (N / 4);
#pragma unroll 1
    for (int it = 0; it < 16; it++) {
        const int kb = kb0 + it * 64;                 // key within batch
        const int ktile = batch * 256 + (kb >> 4);

        // ---- S = q''.k^T ----
        f32x4 sv[4];
#pragma unroll
        for (int nt = 0; nt < 4; nt++) sv[nt] = (f32x4){0.f, 0.f, 0.f, 0.f};
#pragma unroll
        for (int ks = 0; ks < 4; ks++) {
#pragma unroll
            for (int nt = 0; nt < 4; nt++) {
                bf16x8 bk =
                    *(const bf16x8*)(kf + (((size_t)(ktile + nt) * 4 + ks) * 64 + lane) * 8);
                sv[nt] = MFMA16(aq[ks], bk, sv[nt]);
            }
        }

        // ---- P = exp2(S) -> wave-private LDS strip -> A-fragments ----
#pragma unroll
        for (int nt = 0; nt < 4; nt++)
#pragma unroll
            for (int rg = 0; rg < 4; rg++)
                Ps[(quad * 4 + rg) * 72 + nt * 16 + l16] = (bf16)EXP2F(sv[nt][rg]);

        bf16x8 ap[2];
#pragma unroll
        for (int ks2 = 0; ks2 < 2; ks2++)
            ap[ks2] = *(const bf16x8*)&Ps[l16 * 72 + ks2 * 32 + quad * 8];

        // ---- O += P.V ----
        const size_t vg = batch * 128 + (kb >> 5);
#pragma unroll
        for (int ot = 0; ot < 8; ot++) {
            bf16x8 bv0 = *(const bf16x8*)(vf + (((vg + 0) * 8 + ot) * 64 + lane) * 8);
            bf16x8 bv1 = *(const bf16x8*)(vf + (((vg + 1) * 8 + ot) * 64 + lane) * 8);
            oacc[ot] = MFMA16(ap[0], bv0, oacc[ot]);
            oacc[ot] = MFMA16(ap[1], bv1, oacc[ot]);
        }
        // ---- l += P.ones ----
        oacc[8] = MFMA16(ap[0], vone, oacc[8]);
        oacc[8] = MFMA16(ap[1], vone, oacc[8]);
    }

    // ---- combine the 4 key-split partials through LDS (fp32, exact-ish) ----
    __syncthreads();  // Ps strips dead after this
    float* __restrict__ Rs = (float*)smem;  // [3][2][16][148]
    if (ks_i > 0) {
        float* __restrict__ dst = Rs + ((ks_i - 1) * 2 + qw_i) * (16 * 148);
#pragma unroll
        for (int t = 0; t < 9; t++)
#pragma unroll
            for (int rg = 0; rg < 4; rg++)
                dst[(quad * 4 + rg) * 148 + t * 16 + l16] = oacc[t][rg];
    }
    __syncthreads();
    if (ks_i == 0) {
#pragma unroll
        for (int sIdx = 0; sIdx < 3; sIdx++) {
            const float* __restrict__ src = Rs + (sIdx * 2 + qw_i) * (16 * 148);
#pragma unroll
            for (int t = 0; t < 9; t++)
#pragma unroll
                for (int rg = 0; rg < 4; rg++)
                    oacc[t][rg] += src[(quad * 4 + rg) * 148 + t * 16 + l16];
        }
        // epilogue: y = O / l
#pragma unroll
        for (int rg = 0; rg < 4; rg++) {
            const float rl = 1.0f / oacc[8][rg];
            float* __restrict__ yrow = out + ((size_t)qt * 16 + quad * 4 + rg) * D;
#pragma unroll
            for (int t = 0; t < 8; t++)
                yrow[t * 16 + l16] = oacc[t][rg] * rl;
        }
    }
}

// ---------------------------------------------------------------------------
extern "C" void kernel_launch(void* const* d_in, const int* in_sizes, int n_in,
                              void* d_out, int out_size, void* d_ws, size_t ws_size,
                              hipStream_t stream) {
    const float* x = (const float*)d_in[0];
    const float* Wq = (const float*)d_in[1];
    const float* Wk = (const float*)d_in[2];
    const float* Wv = (const float*)d_in[3];
    float* y = (float*)d_out;

    // ws: qf 4MB | kf 4MB | vf 4MB
    bf16* qf = (bf16*)d_ws;
    bf16* kf = qf + (size_t)ROWS * D;
    bf16* vf = kf + (size_t)ROWS * D;

    proj_all<<<512, 256, 0, stream>>>(x, Wq, Wk, Wv, qf, kf, vf);
    flash<<<512, 512, 0, stream>>>(qf, kf, vf, y);
}

// Round 5
// 162.269 us; speedup vs baseline: 2.8009x; 1.1416x over previous
//
#include <hip/hip_runtime.h>

// ---------------------------------------------------------------------------
// Attention: y = softmax( (xWq^T)(xWk^T)^T / sqrt(128) ) (xWv^T)
// B=4, N=4096, H=OUT=128. fp32 I/O, bf16 MFMA compute.
//
// R5: two fixes from r4 counters.
//  (a) flash had VGPR_Count=64 (launch_bounds min-occupancy arg let the
//      allocator chase 8 waves/EU) -> serialized vmcnt(0) loads. Pin the
//      budget with amdgpu_waves_per_eu(4,4) => exactly 128 VGPRs, batch all
//      16 K / 16 V fragment loads per iter.
//  (b) proj_all (~80us!) wrote the swizzled layouts via 48 scalar scattered
//      2B global stores per lane. Now: C-layout -> wave-private LDS ->
//      fragment-layout ds_read_b128 -> coalesced 1KB dwordx4 global stores.
// ---------------------------------------------------------------------------

typedef __bf16 bf16;
typedef __attribute__((ext_vector_type(8))) __bf16 bf16x8;
typedef __attribute__((ext_vector_type(4))) float f32x4;

#define MFMA16(a, b, c) __builtin_amdgcn_mfma_f32_16x16x32_bf16(a, b, c, 0, 0, 0)

#if __has_builtin(__builtin_amdgcn_exp2f)
#define EXP2F(x) __builtin_amdgcn_exp2f(x)
#else
#define EXP2F(x) exp2f(x)
#endif

static constexpr int BATCH = 4;
static constexpr int N = 4096;
static constexpr int D = 128;
static constexpr int ROWS = BATCH * N;  // 16384
// fold 1/sqrt(128) and log2(e) into q so softmax is raw exp2
static constexpr float QSCALE = 0.088388347648318447f * 1.4426950408889634f;

__device__ inline bf16x8 ld8_f32_bf16(const float* __restrict__ p) {
    f32x4 a = *(const f32x4*)p;
    f32x4 b = *(const f32x4*)(p + 4);
    bf16x8 r;
    r[0] = (bf16)a[0]; r[1] = (bf16)a[1]; r[2] = (bf16)a[2]; r[3] = (bf16)a[3];
    r[4] = (bf16)b[0]; r[5] = (bf16)b[1]; r[6] = (bf16)b[2]; r[7] = (bf16)b[3];
    return r;
}

// Fragment layouts (16x16x32 bf16; lane = quad*16 + l16):
//  qf/kf: (tile,row,d) -> ((tile*4 + (d>>5))*64 + ((d&31)>>3)*16 + row)*8 + (d&7)
//  vf:    (o,key)      -> ((vg*8 + (o>>4))*64 + ((key&31)>>3)*16 + (o&15))*8 + (key&7)
//         with vg = batch*128 + (key_in_batch>>5)

// ---------------------------------------------------------------------------
// proj_all: grid 1024 x 256. Block = 16 tokens (1 tile). Waves: 0 -> Q,
// 1 -> K (8 d-tiles each), 2 -> V o 0..63, 3 -> V o 64..127.
// All global stores coalesced dwordx4 via LDS transpose.
// ---------------------------------------------------------------------------
__global__ __launch_bounds__(256) __attribute__((amdgpu_waves_per_eu(4, 4)))
void proj_all(const float* __restrict__ x,
              const float* __restrict__ Wq,
              const float* __restrict__ Wk,
              const float* __restrict__ Wv,
              bf16* __restrict__ qf,
              bf16* __restrict__ kf,
              bf16* __restrict__ vf) {
    // wave-private transpose buffers (no barriers needed)
    __shared__ __attribute__((aligned(16))) bf16 Tqk[2][16][136];  // [row][d]
    __shared__ __attribute__((aligned(16))) bf16 Tv[2][64][24];    // [o][key]

    const int lane = threadIdx.x & 63;
    const int w = threadIdx.x >> 6;
    const int l16 = lane & 15;
    const int quad = lane >> 4;
    const int tile = blockIdx.x;       // 16-token tile
    const int tok0 = tile * 16;

    // x fragments (A and B lane layouts are identical)
    bf16x8 xa[4];
#pragma unroll
    for (int ks = 0; ks < 4; ks++)
        xa[ks] = ld8_f32_bf16(x + (tok0 + l16) * D + ks * 32 + quad * 8);

    if (w < 2) {
        // ---- Q (w=0) or K (w=1) ----
        const float* __restrict__ W = (w == 0) ? Wq : Wk;
        bf16* __restrict__ outp = (w == 0) ? qf : kf;
        const float scale = (w == 0) ? QSCALE : 1.0f;
#pragma unroll
        for (int nt = 0; nt < 8; nt++) {
            f32x4 acc = {0.f, 0.f, 0.f, 0.f};
#pragma unroll
            for (int ks = 0; ks < 4; ks++) {
                bf16x8 bw = ld8_f32_bf16(W + (nt * 16 + l16) * D + ks * 32 + quad * 8);
                acc = MFMA16(xa[ks], bw, acc);
            }
            // C elem (row=quad*4+rg, d=nt*16+l16) -> LDS [row][d]
#pragma unroll
            for (int rg = 0; rg < 4; rg++)
                Tqk[w][quad * 4 + rg][nt * 16 + l16] = (bf16)(acc[rg] * scale);
        }
        // read back in fragment layout (row=l16, d=ks*32+quad*8..+7), store 1KB
#pragma unroll
        for (int ks = 0; ks < 4; ks++) {
            bf16x8 frag = *(const bf16x8*)&Tqk[w][l16][ks * 32 + quad * 8];
            *(bf16x8*)(outp + (((size_t)tile * 4 + ks) * 64 + lane) * 8) = frag;
        }
    } else {
        // ---- V: o-range by wave ----
        const int vw = w - 2;
        const int mt0v = vw * 4;  // o base / 16
#pragma unroll
        for (int mi = 0; mi < 4; mi++) {
            const int mt = mt0v + mi;
            f32x4 acc = {0.f, 0.f, 0.f, 0.f};
#pragma unroll
            for (int ks = 0; ks < 4; ks++) {
                bf16x8 aw = ld8_f32_bf16(Wv + (mt * 16 + l16) * D + ks * 32 + quad * 8);
                acc = MFMA16(aw, xa[ks], acc);
            }
            // C elem (o = mt*16+quad*4+rg, key_local = l16) -> LDS [o][key]
#pragma unroll
            for (int rg = 0; rg < 4; rg++)
                Tv[vw][mi * 16 + quad * 4 + rg][l16] = (bf16)acc[rg];
        }
        const int batch = tok0 >> 12;
        const int tokb = tok0 & (N - 1);
        const size_t vg = batch * 128 + (tokb >> 5);
        const int q0v = (tokb & 31) >> 3;  // 0 or 2 (which half of the 32-key group)
        const int dq = (lane >> 4) & 1;
        const int o15 = lane & 15;
#pragma unroll
        for (int h = 0; h < 2; h++) {
            const int dm = (lane >> 5) + 2 * h;  // o-tile within this wave's 4
            bf16x8 frag = *(const bf16x8*)&Tv[vw][dm * 16 + o15][dq * 8];
            *(bf16x8*)(vf + ((((vg)*8 + mt0v + dm) * 64 + (q0v + dq) * 16 + o15) * 8)) =
                frag;
        }
    }
}

// ---------------------------------------------------------------------------
// flash: grid 512 x 512. Block = 2 q-tiles (32 rows) x 4 key-splits.
// Wave (qw_i = w&1, ks_i = w>>1) does q-tile qw_i over keys [ks_i*1024,+1024),
// 16 iters of 64 keys. Q in registers; fp32 split-combine via LDS; y direct.
// amdgpu_waves_per_eu(4,4) pins VGPR budget at 128 (the r2/r4 fix).
// ---------------------------------------------------------------------------
__global__ __launch_bounds__(512) __attribute__((amdgpu_waves_per_eu(4, 4)))
void flash(const bf16* __restrict__ qf,
           const bf16* __restrict__ kf,
           const bf16* __restrict__ vf,
           float* __restrict__ out) {
    // Alias: main loop Ps strips (8 x 16x72 bf16 = 18432B); after barrier
    // Rs[3][2][16][148] f32 = 56832B.
    __shared__ __attribute__((aligned(16))) unsigned char smem[56832];

    const int lane = threadIdx.x & 63;
    const int w = threadIdx.x >> 6;  // 0..7
    const int l16 = lane & 15;
    const int quad = lane >> 4;
    const int qw_i = w & 1;
    const int ks_i = w >> 1;

    // XCD swizzle: bid%8 = XCD; 2 XCDs per batch -> K/V L2-resident.
    const int lo = blockIdx.x & 7;
    const int hi = blockIdx.x >> 3;
    const int batch = lo >> 1;
    const int qpair = hi * 2 + (lo & 1);
    const int qt = batch * 256 + qpair * 2 + qw_i;  // global q-tile

    bf16* __restrict__ Ps = (bf16*)smem + w * (16 * 72);

    bf16x8 aq[4];
#pragma unroll
    for (int ks = 0; ks < 4; ks++)
        aq[ks] = *(const bf16x8*)(qf + (((size_t)qt * 4 + ks) * 64 + lane) * 8);

    f32x4 oacc[9];
#pragma unroll
    for (int i = 0; i < 9; i++) oacc[i] = (f32x4){0.f, 0.f, 0.f, 0.f};

    bf16x8 vone;
#pragma unroll
    for (int j = 0; j < 8; j++) vone[j] = (bf16)1.0f;

    const int kb0 = ks_i * (N / 4);
#pragma unroll 1
    for (int it = 0; it < 16; it++) {
        const int kb = kb0 + it * 64;
        const int ktile = batch * 256 + (kb >> 4);

        // ---- all 16 K fragments issued as one batch ----
        bf16x8 bk[4][4];
#pragma unroll
        for (int nt = 0; nt < 4; nt++)
#pragma unroll
            for (int ks = 0; ks < 4; ks++)
                bk[nt][ks] =
                    *(const bf16x8*)(kf + (((size_t)(ktile + nt) * 4 + ks) * 64 + lane) * 8);

        // ---- S = q''.k^T ----
        f32x4 sv[4];
#pragma unroll
        for (int nt = 0; nt < 4; nt++) sv[nt] = (f32x4){0.f, 0.f, 0.f, 0.f};
#pragma unroll
        for (int ks = 0; ks < 4; ks++)
#pragma unroll
            for (int nt = 0; nt < 4; nt++)
                sv[nt] = MFMA16(aq[ks], bk[nt][ks], sv[nt]);

        // ---- V fragments issued now; latency hides under exp2 + LDS ----
        const size_t vg = batch * 128 + (kb >> 5);
        bf16x8 bv[8][2];
#pragma unroll
        for (int ot = 0; ot < 8; ot++)
#pragma unroll
            for (int g2 = 0; g2 < 2; g2++)
                bv[ot][g2] =
                    *(const bf16x8*)(vf + (((vg + g2) * 8 + ot) * 64 + lane) * 8);

        // ---- P = exp2(S) -> wave-private LDS strip -> A-fragments ----
#pragma unroll
        for (int nt = 0; nt < 4; nt++)
#pragma unroll
            for (int rg = 0; rg < 4; rg++)
                Ps[(quad * 4 + rg) * 72 + nt * 16 + l16] = (bf16)EXP2F(sv[nt][rg]);

        bf16x8 ap[2];
#pragma unroll
        for (int ks2 = 0; ks2 < 2; ks2++)
            ap[ks2] = *(const bf16x8*)&Ps[l16 * 72 + ks2 * 32 + quad * 8];

        // ---- O += P.V ----
#pragma unroll
        for (int ot = 0; ot < 8; ot++) {
            oacc[ot] = MFMA16(ap[0], bv[ot][0], oacc[ot]);
            oacc[ot] = MFMA16(ap[1], bv[ot][1], oacc[ot]);
        }
        oacc[8] = MFMA16(ap[0], vone, oacc[8]);
        oacc[8] = MFMA16(ap[1], vone, oacc[8]);
    }

    // ---- combine the 4 key-split partials through LDS (fp32) ----
    __syncthreads();
    float* __restrict__ Rs = (float*)smem;  // [3][2][16][148]
    if (ks_i > 0) {
        float* __restrict__ dst = Rs + ((ks_i - 1) * 2 + qw_i) * (16 * 148);
#pragma unroll
        for (int t = 0; t < 9; t++)
#pragma unroll
            for (int rg = 0; rg < 4; rg++)
                dst[(quad * 4 + rg) * 148 + t * 16 + l16] = oacc[t][rg];
    }
    __syncthreads();
    if (ks_i == 0) {
#pragma unroll
        for (int sIdx = 0; sIdx < 3; sIdx++) {
            const float* __restrict__ src = Rs + (sIdx * 2 + qw_i) * (16 * 148);
#pragma unroll
            for (int t = 0; t < 9; t++)
#pragma unroll
                for (int rg = 0; rg < 4; rg++)
                    oacc[t][rg] += src[(quad * 4 + rg) * 148 + t * 16 + l16];
        }
#pragma unroll
        for (int rg = 0; rg < 4; rg++) {
            const float rl = 1.0f / oacc[8][rg];
            float* __restrict__ yrow = out + ((size_t)qt * 16 + quad * 4 + rg) * D;
#pragma unroll
            for (int t = 0; t < 8; t++)
                yrow[t * 16 + l16] = oacc[t][rg] * rl;
        }
    }
}

// ---------------------------------------------------------------------------
extern "C" void kernel_launch(void* const* d_in, const int* in_sizes, int n_in,
                              void* d_out, int out_size, void* d_ws, size_t ws_size,
                              hipStream_t stream) {
    const float* x = (const float*)d_in[0];
    const float* Wq = (const float*)d_in[1];
    const float* Wk = (const float*)d_in[2];
    const float* Wv = (const float*)d_in[3];
    float* y = (float*)d_out;

    bf16* qf = (bf16*)d_ws;                 // 4MB
    bf16* kf = qf + (size_t)ROWS * D;       // 4MB
    bf16* vf = kf + (size_t)ROWS * D;       // 4MB

    proj_all<<<1024, 256, 0, stream>>>(x, Wq, Wk, Wv, qf, kf, vf);
    flash<<<512, 512, 0, stream>>>(qf, kf, vf, y);
}

// Round 6
// 122.943 us; speedup vs baseline: 3.6968x; 1.3199x over previous
//
#include <hip/hip_runtime.h>

// ---------------------------------------------------------------------------
// Attention: y = softmax( (xWq^T)(xWk^T)^T / sqrt(128) ) (xWv^T)
// B=4, N=4096, H=OUT=128. fp32 I/O, bf16 MFMA compute.
//
// R6:
//  flash: was L1/L2-ingest-bound (2.1GB: each wave pulled 32KB K+V per iter
//  for only 16 q-rows). Now 2 q-tiles/wave -> ingest halved; explicit load
//  batches pinned with sched_barrier(0); next-iter K prefetch; VGPR budget
//  pinned 256 via waves_per_eu(2,2).
//  proj: was latency-bound on scattered weight gathers. Weights now staged
//  per-block into LDS (3 x 32KB phases, coalesced), fragments served by
//  ds_read_b128.
// ---------------------------------------------------------------------------

typedef __bf16 bf16;
typedef __attribute__((ext_vector_type(8))) __bf16 bf16x8;
typedef __attribute__((ext_vector_type(4))) float f32x4;

#define MFMA16(a, b, c) __builtin_amdgcn_mfma_f32_16x16x32_bf16(a, b, c, 0, 0, 0)

#if __has_builtin(__builtin_amdgcn_exp2f)
#define EXP2F(x) __builtin_amdgcn_exp2f(x)
#else
#define EXP2F(x) exp2f(x)
#endif

static constexpr int BATCH = 4;
static constexpr int N = 4096;
static constexpr int D = 128;
static constexpr int ROWS = BATCH * N;  // 16384
// fold 1/sqrt(128) and log2(e) into q so softmax is raw exp2
static constexpr float QSCALE = 0.088388347648318447f * 1.4426950408889634f;

__device__ inline bf16x8 ld8_f32_bf16(const float* __restrict__ p) {
    f32x4 a = *(const f32x4*)p;
    f32x4 b = *(const f32x4*)(p + 4);
    bf16x8 r;
    r[0] = (bf16)a[0]; r[1] = (bf16)a[1]; r[2] = (bf16)a[2]; r[3] = (bf16)a[3];
    r[4] = (bf16)b[0]; r[5] = (bf16)b[1]; r[6] = (bf16)b[2]; r[7] = (bf16)b[3];
    return r;
}

// Fragment layouts (16x16x32 bf16; lane = quad*16 + l16):
//  qf/kf: (tile,row,d) -> ((tile*4 + (d>>5))*64 + ((d&31)>>3)*16 + row)*8 + (d&7)
//  vf:    (o,key)      -> ((vg*8 + (o>>4))*64 + ((key&31)>>3)*16 + (o&15))*8 + (key&7)
//         with vg = batch*128 + (key_in_batch>>5)

// ---------------------------------------------------------------------------
// proj_all: grid 256 x 256 (4 waves). Block = 64 tokens (4 tiles, one/wave).
// Loop over 3 phases (Wq, Wk, Wv): stage W into LDS as bf16 fragments
// (coalesced fp32 reads), barrier, each wave MFMAs its token tile, transposes
// C through per-wave LDS scratch, stores coalesced dwordx4.
// ---------------------------------------------------------------------------
__global__ __launch_bounds__(256) void proj_all(const float* __restrict__ x,
                                                const float* __restrict__ Wq,
                                                const float* __restrict__ Wk,
                                                const float* __restrict__ Wv,
                                                bf16* __restrict__ qf,
                                                bf16* __restrict__ kf,
                                                bf16* __restrict__ vf) {
    __shared__ __attribute__((aligned(16))) bf16 Wl[D * D];          // 32 KB
    __shared__ __attribute__((aligned(16))) bf16 Scr[4][2560];       // 20 KB scratch

    const int lane = threadIdx.x & 63;
    const int w = threadIdx.x >> 6;  // 0..3 = token tile
    const int l16 = lane & 15;
    const int quad = lane >> 4;
    const int tok0 = blockIdx.x * 64 + w * 16;
    const int tile = tok0 >> 4;

    // x fragments (held across all 3 phases; A and B lane layouts identical)
    bf16x8 xa[4];
#pragma unroll
    for (int ks = 0; ks < 4; ks++)
        xa[ks] = ld8_f32_bf16(x + (tok0 + l16) * D + ks * 32 + quad * 8);

    const float* Ws[3] = {Wq, Wk, Wv};

    for (int ph = 0; ph < 3; ph++) {
        // ---- stage W[ph] into LDS in fragment layout ----
        __syncthreads();  // previous phase done reading Wl
        {
            const float* __restrict__ W = Ws[ph];
            const int r = threadIdx.x >> 1;
            const int c0 = (threadIdx.x & 1) * 64;
#pragma unroll
            for (int g = 0; g < 8; g++) {
                const int h = c0 + g * 8;
                bf16x8 v = ld8_f32_bf16(W + r * D + h);
                const int frag = (r >> 4) * 4 + (h >> 5);
                const int ln = ((h & 31) >> 3) * 16 + (r & 15);
                *(bf16x8*)&Wl[(frag * 64 + ln) * 8] = v;
            }
        }
        __syncthreads();

        if (ph < 2) {
            // ---- Q or K: B = W fragment, A = x ----
            bf16* __restrict__ outp = (ph == 0) ? qf : kf;
            const float scale = (ph == 0) ? QSCALE : 1.0f;
            bf16* __restrict__ T = Scr[w];  // [16][136]
#pragma unroll
            for (int nt = 0; nt < 8; nt++) {
                f32x4 acc = {0.f, 0.f, 0.f, 0.f};
#pragma unroll
                for (int ks = 0; ks < 4; ks++) {
                    bf16x8 bw = *(const bf16x8*)&Wl[((nt * 4 + ks) * 64 + lane) * 8];
                    acc = MFMA16(xa[ks], bw, acc);
                }
#pragma unroll
                for (int rg = 0; rg < 4; rg++)
                    T[(quad * 4 + rg) * 136 + nt * 16 + l16] = (bf16)(acc[rg] * scale);
            }
            // readback fragments, coalesced 1KB stores
#pragma unroll
            for (int ks = 0; ks < 4; ks++) {
                bf16x8 frag = *(const bf16x8*)&T[l16 * 136 + ks * 32 + quad * 8];
                *(bf16x8*)(outp + (((size_t)tile * 4 + ks) * 64 + lane) * 8) = frag;
            }
        } else {
            // ---- V: A = Wv fragment, B = x ----
            bf16* __restrict__ T = Scr[w];  // [128][20]
#pragma unroll
            for (int mt = 0; mt < 8; mt++) {
                f32x4 acc = {0.f, 0.f, 0.f, 0.f};
#pragma unroll
                for (int ks = 0; ks < 4; ks++) {
                    bf16x8 aw = *(const bf16x8*)&Wl[((mt * 4 + ks) * 64 + lane) * 8];
                    acc = MFMA16(aw, xa[ks], acc);
                }
                // C: row = o = mt*16+quad*4+rg, col = token = l16
#pragma unroll
                for (int rg = 0; rg < 4; rg++)
                    T[(mt * 16 + quad * 4 + rg) * 20 + l16] = (bf16)acc[rg];
            }
            const int batch = tok0 >> 12;
            const int tokb = tok0 & (N - 1);
            const size_t vg = batch * 128 + (tokb >> 5);
            const int q0v = (tokb & 31) >> 3;  // 0 or 2
            const int dq = (lane >> 4) & 1;
            const int o15 = lane & 15;
#pragma unroll
            for (int s = 0; s < 4; s++) {
                const int ot = s * 2 + (lane >> 5);
                bf16x8 frag = *(const bf16x8*)&T[(ot * 16 + o15) * 20 + dq * 8];
                *(bf16x8*)(vf + ((vg * 8 + ot) * 64 + (q0v + dq) * 16 + o15) * 8) = frag;
            }
        }
    }
}

// ---------------------------------------------------------------------------
// flash: grid 512 x 256 (4 waves). Block = 32 q-rows (2 tiles); wave w =
// key-split w (1024 keys, 16 iters of 64). Each wave computes BOTH q-tiles
// (K/V fragments reused -> ingest halved). Load batches pinned with
// sched_barrier; next-iter K prefetched. fp32 split-combine via LDS.
// ---------------------------------------------------------------------------
__global__ __launch_bounds__(256) __attribute__((amdgpu_waves_per_eu(2, 2)))
void flash(const bf16* __restrict__ qf,
           const bf16* __restrict__ kf,
           const bf16* __restrict__ vf,
           float* __restrict__ out) {
    // Alias: main loop Ps strips (4 waves x 2 tiles x 16x72 bf16 = 18432B);
    // combine Rs[3][2][16][148] f32 = 56832B.
    __shared__ __attribute__((aligned(16))) unsigned char smem[56832];

    const int lane = threadIdx.x & 63;
    const int w = threadIdx.x >> 6;  // 0..3 = key split
    const int l16 = lane & 15;
    const int quad = lane >> 4;

    // XCD swizzle: bid%8 = XCD; 2 XCDs per batch -> K/V (2MB) L2-resident.
    const int lo = blockIdx.x & 7;
    const int hi = blockIdx.x >> 3;
    const int batch = lo >> 1;
    const int qpair = hi * 2 + (lo & 1);        // 0..127
    const int qtg0 = batch * 256 + qpair * 2;   // global q-tile of tile 0

    bf16* __restrict__ Psw = (bf16*)smem + w * (2 * 16 * 72);

    bf16x8 aq[2][4];
#pragma unroll
    for (int qt = 0; qt < 2; qt++)
#pragma unroll
        for (int ks = 0; ks < 4; ks++)
            aq[qt][ks] =
                *(const bf16x8*)(qf + (((size_t)(qtg0 + qt) * 4 + ks) * 64 + lane) * 8);

    f32x4 oacc[2][9];
#pragma unroll
    for (int qt = 0; qt < 2; qt++)
#pragma unroll
        for (int i = 0; i < 9; i++) oacc[qt][i] = (f32x4){0.f, 0.f, 0.f, 0.f};

    bf16x8 vone;
#pragma unroll
    for (int j = 0; j < 8; j++) vone[j] = (bf16)1.0f;

    const int kb0 = w * (N / 4);

    // preload K batch for it=0
    bf16x8 bk[4][4];
    {
        const int ktile = batch * 256 + (kb0 >> 4);
#pragma unroll
        for (int nt = 0; nt < 4; nt++)
#pragma unroll
            for (int ks = 0; ks < 4; ks++)
                bk[nt][ks] = *(const bf16x8*)(kf +
                    (((size_t)(ktile + nt) * 4 + ks) * 64 + lane) * 8);
    }
    __builtin_amdgcn_sched_barrier(0);

#pragma unroll 1
    for (int it = 0; it < 16; it++) {
        const int kb = kb0 + it * 64;

        // ---- S = q''.k^T (both tiles share bk) ----
        f32x4 sv[2][4];
#pragma unroll
        for (int qt = 0; qt < 2; qt++)
#pragma unroll
            for (int nt = 0; nt < 4; nt++) sv[qt][nt] = (f32x4){0.f, 0.f, 0.f, 0.f};
#pragma unroll
        for (int ks = 0; ks < 4; ks++)
#pragma unroll
            for (int nt = 0; nt < 4; nt++) {
                sv[0][nt] = MFMA16(aq[0][ks], bk[nt][ks], sv[0][nt]);
                sv[1][nt] = MFMA16(aq[1][ks], bk[nt][ks], sv[1][nt]);
            }
        __builtin_amdgcn_sched_barrier(0);

        // ---- V batch 1 (ot 0..3), latency hides under exp2 ----
        const size_t vg = batch * 128 + (kb >> 5);
        bf16x8 bv1[4][2];
#pragma unroll
        for (int ot = 0; ot < 4; ot++)
#pragma unroll
            for (int g2 = 0; g2 < 2; g2++)
                bv1[ot][g2] =
                    *(const bf16x8*)(vf + (((vg + g2) * 8 + ot) * 64 + lane) * 8);
        __builtin_amdgcn_sched_barrier(0);

        // ---- P = exp2(S) -> LDS strips ----
#pragma unroll
        for (int qt = 0; qt < 2; qt++)
#pragma unroll
            for (int nt = 0; nt < 4; nt++)
#pragma unroll
                for (int rg = 0; rg < 4; rg++)
                    Psw[qt * 1152 + (quad * 4 + rg) * 72 + nt * 16 + l16] =
                        (bf16)EXP2F(sv[qt][nt][rg]);
        __builtin_amdgcn_sched_barrier(0);

        // ---- V batch 2 (ot 4..7) ----
        bf16x8 bv2[4][2];
#pragma unroll
        for (int ot = 0; ot < 4; ot++)
#pragma unroll
            for (int g2 = 0; g2 < 2; g2++)
                bv2[ot][g2] =
                    *(const bf16x8*)(vf + (((vg + g2) * 8 + ot + 4) * 64 + lane) * 8);
        __builtin_amdgcn_sched_barrier(0);

        // ---- prefetch next iter's K ----
        {
            const int itn = (it < 15) ? it + 1 : 15;
            const int kbn = kb0 + itn * 64;
            const int ktn = batch * 256 + (kbn >> 4);
#pragma unroll
            for (int nt = 0; nt < 4; nt++)
#pragma unroll
                for (int ks = 0; ks < 4; ks++)
                    bk[nt][ks] = *(const bf16x8*)(kf +
                        (((size_t)(ktn + nt) * 4 + ks) * 64 + lane) * 8);
        }
        __builtin_amdgcn_sched_barrier(0);

        // ---- P back as A-fragments ----
        bf16x8 ap[2][2];
#pragma unroll
        for (int qt = 0; qt < 2; qt++)
#pragma unroll
            for (int g2 = 0; g2 < 2; g2++)
                ap[qt][g2] =
                    *(const bf16x8*)&Psw[qt * 1152 + l16 * 72 + g2 * 32 + quad * 8];

        // ---- O += P.V ----
#pragma unroll
        for (int ot = 0; ot < 4; ot++)
#pragma unroll
            for (int g2 = 0; g2 < 2; g2++) {
                oacc[0][ot] = MFMA16(ap[0][g2], bv1[ot][g2], oacc[0][ot]);
                oacc[1][ot] = MFMA16(ap[1][g2], bv1[ot][g2], oacc[1][ot]);
            }
#pragma unroll
        for (int ot = 0; ot < 4; ot++)
#pragma unroll
            for (int g2 = 0; g2 < 2; g2++) {
                oacc[0][ot + 4] = MFMA16(ap[0][g2], bv2[ot][g2], oacc[0][ot + 4]);
                oacc[1][ot + 4] = MFMA16(ap[1][g2], bv2[ot][g2], oacc[1][ot + 4]);
            }
#pragma unroll
        for (int qt = 0; qt < 2; qt++)
#pragma unroll
            for (int g2 = 0; g2 < 2; g2++)
                oacc[qt][8] = MFMA16(ap[qt][g2], vone, oacc[qt][8]);
    }

    // ---- combine the 4 key-split partials through LDS (fp32) ----
    __syncthreads();
    float* __restrict__ Rs = (float*)smem;  // [3][2][16][148]
    if (w > 0) {
#pragma unroll
        for (int qt = 0; qt < 2; qt++) {
            float* __restrict__ dst = Rs + ((w - 1) * 2 + qt) * (16 * 148);
#pragma unroll
            for (int t = 0; t < 9; t++)
#pragma unroll
                for (int rg = 0; rg < 4; rg++)
                    dst[(quad * 4 + rg) * 148 + t * 16 + l16] = oacc[qt][t][rg];
        }
    }
    __syncthreads();
    if (w == 0) {
#pragma unroll
        for (int qt = 0; qt < 2; qt++) {
#pragma unroll
            for (int sIdx = 0; sIdx < 3; sIdx++) {
                const float* __restrict__ src = Rs + (sIdx * 2 + qt) * (16 * 148);
#pragma unroll
                for (int t = 0; t < 9; t++)
#pragma unroll
                    for (int rg = 0; rg < 4; rg++)
                        oacc[qt][t][rg] += src[(quad * 4 + rg) * 148 + t * 16 + l16];
            }
#pragma unroll
            for (int rg = 0; rg < 4; rg++) {
                const float rl = 1.0f / oacc[qt][8][rg];
                float* __restrict__ yrow =
                    out + (((size_t)(qtg0 + qt)) * 16 + quad * 4 + rg) * D;
#pragma unroll
                for (int t = 0; t < 8; t++)
                    yrow[t * 16 + l16] = oacc[qt][t][rg] * rl;
            }
        }
    }
}

// ---------------------------------------------------------------------------
extern "C" void kernel_launch(void* const* d_in, const int* in_sizes, int n_in,
                              void* d_out, int out_size, void* d_ws, size_t ws_size,
                              hipStream_t stream) {
    const float* x = (const float*)d_in[0];
    const float* Wq = (const float*)d_in[1];
    const float* Wk = (const float*)d_in[2];
    const float* Wv = (const float*)d_in[3];
    float* y = (float*)d_out;

    bf16* qf = (bf16*)d_ws;            // 4MB
    bf16* kf = qf + (size_t)ROWS * D;  // 4MB
    bf16* vf = kf + (size_t)ROWS * D;  // 4MB

    proj_all<<<256, 256, 0, stream>>>(x, Wq, Wk, Wv, qf, kf, vf);
    flash<<<512, 256, 0, stream>>>(qf, kf, vf, y);
}